// Round 11
// baseline (6451.119 us; speedup 1.0000x reference)
//
#include <hip/hip_runtime.h>
#include <hip/hip_cooperative_groups.h>
#include <type_traits>

namespace cg = cooperative_groups;

constexpr int NN = 5000;   // nodes
constexpr int NP = 5120;   // padded nodes / K
constexpr int TT = 12;     // enc/dec length
constexpr int UU = 32;     // rnn units
constexpr int FP = 48;     // padded feature rows
constexpr int FR = 33;     // real feature rows (IN+U)
constexpr int DN = 99;     // DIN
constexpr int BN = 16;     // nodes per A-fragment tile
constexpr int BNODE = 32;  // nodes per block (2 fragment tiles)
constexpr int KC = 128;    // K chunk
constexpr int NKC = NP / KC;                 // 40
constexpr int CPW = NKC / 8;                 // 5 chunks per wave (8-way K split)
constexpr int GRID_MM = (NN + BNODE - 1) / BNODE;  // 157
constexpr int CHE = FP * KC;                 // 6144 elements per chunk (frag layout)
constexpr int ACH = BN * KC;                 // 2048 elements per (node-tile, chunk) A frag
constexpr int PB = FP * BNODE;               // 1536 partial elems per wave

typedef __attribute__((ext_vector_type(8))) short short8;
typedef __attribute__((ext_vector_type(4))) float f32x4;

__device__ __forceinline__ unsigned short f2bf(float x) {
  union { float f; unsigned u; } c; c.f = x;
  return (unsigned short)((c.u + 0x7FFFu + ((c.u >> 16) & 1u)) >> 16);
}

// MFMA A-fragment layout for X^T: element (f, node-as-K) -> flat index such
// that a wave's 16B load at base+lane*16 is fully coalesced.
__device__ __forceinline__ int flatXF(int f, int node) {
  int chunk = node >> 7;
  int ks = (node >> 5) & 3;
  int q = (node >> 3) & 3;
  int j = node & 7;
  int t3 = f >> 4;
  int m = f & 15;
  return chunk * CHE + t3 * 2048 + ks * 512 + (m + 16 * q) * 8 + j;
}

__global__ void k_zero(uint4* __restrict__ p, int n) {
  int i = blockIdx.x * 256 + threadIdx.x;
  if (i < n) p[i] = make_uint4(0u, 0u, 0u, 0u);
}

// Output-centric A swizzle: consecutive threads write consecutive 16B of the
// fragment-ordered adjb (perfect write stream).
__global__ void k_cast2(const float* __restrict__ adj, unsigned short* __restrict__ adjb) {
  int gid = blockIdx.x * 256 + threadIdx.x;  // < NP*NP/8
  int tile = gid >> 8;                       // (nt*NKC + c)
  int r2 = gid & 255;
  int nt = tile / NKC, c = tile - nt * NKC;
  int ks = r2 >> 6;
  int qm = r2 & 63;
  int q = qm >> 4, m = qm & 15;
  int n = nt * 16 + m;
  int k = c * 128 + ks * 32 + q * 8;
  union { short8 s; unsigned short u[8]; } o;
  if (n < NN && k < NN) {
    const f32x4* a = reinterpret_cast<const f32x4*>(adj + (size_t)n * NN + k);
    f32x4 x0 = __builtin_nontemporal_load(a);
    f32x4 x1 = __builtin_nontemporal_load(a + 1);
    o.u[0] = f2bf(x0.x); o.u[1] = f2bf(x0.y); o.u[2] = f2bf(x0.z); o.u[3] = f2bf(x0.w);
    o.u[4] = f2bf(x1.x); o.u[5] = f2bf(x1.y); o.u[6] = f2bf(x1.z); o.u[7] = f2bf(x1.w);
  } else {
    o.u[0] = 0; o.u[1] = 0; o.u[2] = 0; o.u[3] = 0;
    o.u[4] = 0; o.u[5] = 0; o.u[6] = 0; o.u[7] = 0;
  }
  *reinterpret_cast<short8*>(adjb + (size_t)gid * 8) = o.s;
}

__global__ void k_initx0(const float* __restrict__ in, float* __restrict__ xf,
                         unsigned short* __restrict__ xb) {
  int n = blockIdx.x * 256 + threadIdx.x;
  if (n >= NP) return;
  float v = (n < NN) ? in[(size_t)n * TT] : 0.f;
  xf[n] = v;
  xb[flatXF(0, n)] = f2bf(v);
}

// One GEMM stage (R5 structure, USEBF hardwired): C^T[f][node] over this
// block's 32 nodes. 8 waves; wave w owns K slice [w*640,+640); A dbuf'd,
// X loads issued first each chunk. COMPILE-TIME unrolled CPW loop (R9
// lesson). No early returns (cooperative grid.sync follows each call).
template <int EPI>
__device__ __forceinline__ void gemm_stage(
    float* __restrict__ smemF,
    const unsigned short* __restrict__ adjb,
    const unsigned short* __restrict__ rhs,
    float* __restrict__ outF, unsigned short* __restrict__ outB,
    const float* __restrict__ s0F, const float* __restrict__ s1F,
    const float* __restrict__ W, const float* __restrict__ bias,
    float* __restrict__ hT, float* __restrict__ uT,
    float* __restrict__ xoF, unsigned short* __restrict__ xoB,
    const float* __restrict__ inp, const float* __restrict__ Wp,
    const float* __restrict__ bp, float* __restrict__ dout,
    int mode, int tnext, int dstep) {
  constexpr int WC = (EPI == 1) ? 64 : 32;
  float* Pv = smemF;
  float* x2s = smemF + PB * 8;
  float* Ws = smemF;  // overlays Pv after reduce

  const int tid = threadIdx.x;
  const int wave = tid >> 6;
  const int lane = tid & 63;
  const int m = lane & 15;
  const int q = lane >> 4;
  const int nodeBase = blockIdx.x * BNODE;

  f32x4 acc[2][3] = {};
  short8 aCur[2][4], aNxt[2][4];

  const unsigned short* aB0 =
      adjb + (size_t)(2 * blockIdx.x) * NKC * ACH + lane * 8;
  const unsigned short* aB1 =
      adjb + (size_t)(2 * blockIdx.x + 1) * NKC * ACH + lane * 8;

  auto loadA = [&](int i, short8 (&b)[2][4]) {
    const int ch = wave * CPW + i;
    const unsigned short* a0 = aB0 + (size_t)ch * ACH;
    const unsigned short* a1 = aB1 + (size_t)ch * ACH;
#pragma unroll
    for (int ks = 0; ks < 4; ++ks) {
      b[0][ks] = *reinterpret_cast<const short8*>(a0 + ks * 512);
      b[1][ks] = *reinterpret_cast<const short8*>(a1 + ks * 512);
    }
  };

  loadA(0, aCur);
#pragma unroll
  for (int i = 0; i < CPW; ++i) {
    const int ch = wave * CPW + i;
    short8 cx[12];
    const unsigned short* xb = rhs + (size_t)ch * CHE + lane * 8;
    // X loads first (older in vmcnt order)...
#pragma unroll
    for (int t3 = 0; t3 < 3; ++t3)
#pragma unroll
      for (int ks = 0; ks < 4; ++ks)
        cx[t3 * 4 + ks] = *(const short8*)(xb + t3 * 2048 + ks * 512);
    // ...then the A prefetch: waiting for cx leaves these in flight.
    if (i + 1 < CPW) loadA(i + 1, aNxt);
#pragma unroll
    for (int ks = 0; ks < 4; ++ks) {
#pragma unroll
      for (int h = 0; h < 2; ++h) {
        acc[h][0] = __builtin_amdgcn_mfma_f32_16x16x32_bf16(cx[ks], aCur[h][ks], acc[h][0], 0, 0, 0);
        acc[h][1] = __builtin_amdgcn_mfma_f32_16x16x32_bf16(cx[4 + ks], aCur[h][ks], acc[h][1], 0, 0, 0);
        acc[h][2] = __builtin_amdgcn_mfma_f32_16x16x32_bf16(cx[8 + ks], aCur[h][ks], acc[h][2], 0, 0, 0);
      }
    }
#pragma unroll
    for (int h = 0; h < 2; ++h)
#pragma unroll
      for (int ks = 0; ks < 4; ++ks) aCur[h][ks] = aNxt[h][ks];
  }

#pragma unroll
  for (int h = 0; h < 2; ++h)
#pragma unroll
    for (int t3 = 0; t3 < 3; ++t3)
#pragma unroll
      for (int r = 0; r < 4; ++r)
        Pv[wave * PB + (t3 * 16 + q * 4 + r) * BNODE + h * 16 + m] = acc[h][t3][r];
  __syncthreads();

  if constexpr (EPI == 0) {
    for (int e = tid; e < PB; e += 512) {
      int f = e >> 5, n = e & 31;
      float v = 0.f;
#pragma unroll
      for (int w = 0; w < 8; ++w) v += Pv[w * PB + e];
      int gn2 = nodeBase + n;
      if (gn2 >= NN) v = 0.f;
      outF[(size_t)f * NP + gn2] = v;
      outB[flatXF(f, gn2)] = f2bf(v);
    }
    __syncthreads();  // Pv reads done before next stage reuses smem
  } else {
    for (int e = tid; e < PB; e += 512) {
      int f = e >> 5, n = e & 31;
      float v = 0.f;
#pragma unroll
      for (int w = 0; w < 8; ++w) v += Pv[w * PB + e];
      x2s[f * 33 + n] = v;
    }
    __syncthreads();
    // Pv is dead; overlay epilogue weights
    for (int i = tid; i < DN * WC; i += 512) Ws[i] = W[i];
    __syncthreads();
    const int nl = tid & 15;
    const int cg = tid >> 4;  // 0..31
    float hwv[2];
#pragma unroll
    for (int nh = 0; nh < 2; ++nh) {
      const int nl2 = nh * 16 + nl;
      const int gn2 = nodeBase + nl2;
      const bool valid = gn2 < NN;
      const int gnc = valid ? gn2 : NN - 1;
      if constexpr (EPI == 1) {
        float a0 = bias[cg], a1 = bias[cg + 32];
        for (int f = 0; f < FR; ++f) {
          float fe = s0F[(size_t)f * NP + gnc];
          a0 += fe * Ws[f * WC + cg]; a1 += fe * Ws[f * WC + cg + 32];
        }
        for (int f = 0; f < FR; ++f) {
          float fe = s1F[(size_t)f * NP + gnc];
          a0 += fe * Ws[(FR + f) * WC + cg]; a1 += fe * Ws[(FR + f) * WC + cg + 32];
        }
        for (int f = 0; f < FR; ++f) {
          float fe = x2s[f * 33 + nl2];
          a0 += fe * Ws[(2 * FR + f) * WC + cg]; a1 += fe * Ws[(2 * FR + f) * WC + cg + 32];
        }
        float r = 1.f / (1.f + expf(-a0));          // r gate (cols 0..31)
        float hv = hT[(size_t)cg * NP + gnc];
        float xc = valid ? r * hv : 0.f;
        xoF[(size_t)(1 + cg) * NP + gn2] = xc;
        xoB[flatXF(1 + cg, gn2)] = f2bf(xc);
        float u = 1.f / (1.f + expf(-a1));          // u gate (cols 32..63)
        uT[(size_t)cg * NP + gn2] = valid ? u : 0.f;
        hwv[nh] = 0.f;
      } else {
        float a0 = bias[cg];
        for (int f = 0; f < FR; ++f) a0 += s0F[(size_t)f * NP + gnc] * Ws[f * WC + cg];
        for (int f = 0; f < FR; ++f) a0 += s1F[(size_t)f * NP + gnc] * Ws[(FR + f) * WC + cg];
        for (int f = 0; f < FR; ++f) a0 += x2s[f * 33 + nl2] * Ws[(2 * FR + f) * WC + cg];
        float c = tanhf(a0);
        float u = uT[(size_t)cg * NP + gnc];
        float h0 = hT[(size_t)cg * NP + gnc];
        float hn = u * h0 + (1.f - u) * c;
        float hw = valid ? hn : 0.f;
        hwv[nh] = hw;
        hT[(size_t)cg * NP + gn2] = hw;
        xoF[(size_t)(1 + cg) * NP + gn2] = hw;
        xoB[flatXF(1 + cg, gn2)] = f2bf(hw);
      }
    }
    if constexpr (EPI == 1) {
      if (tid < BNODE) {
        int g3 = nodeBase + tid;
        float v0 = s0F[g3];
        xoF[g3] = v0;
        xoB[flatXF(0, g3)] = f2bf(v0);
      }
      __syncthreads();  // x2s/Ws reads done before next stage reuses smem
    } else {
      __syncthreads();                 // all x2s reads done
      x2s[cg * 33 + nl] = hwv[0];      // reuse as h scratch [col][node]
      x2s[cg * 33 + 16 + nl] = hwv[1];
      __syncthreads();
      if (tid < BNODE) {
        int g3 = nodeBase + tid;
        bool v3 = g3 < NN;
        float x0 = 0.f;
        if (mode == 0) {
          x0 = v3 ? inp[(size_t)g3 * TT + tnext] : 0.f;
        } else if (mode == 2) {
          float p = bp[0];
          for (int j = 0; j < UU; ++j) p += x2s[j * 33 + tid] * Wp[j];
          if (v3) dout[(size_t)g3 * TT + dstep] = p;
          x0 = v3 ? p : 0.f;
        }
        xoF[g3] = x0;
        xoB[flatXF(0, g3)] = f2bf(x0);
      }
      __syncthreads();  // x2s reads done before next stage reuses smem
    }
  }
}

struct MegaArgs {
  const unsigned short* adjb;
  unsigned short* xhGb; float* xhGf;
  unsigned short* xhCb; float* xhCf;
  unsigned short* x1b;  float* x1f;
  float* hT; float* uT;
  const float* eWg; const float* eBg; const float* eWc; const float* eBc;
  const float* dWg; const float* dBg; const float* dWc; const float* dBc;
  const float* Wp; const float* bp;
  const float* inp; float* dout;
};

// Persistent cooperative megakernel: all 24 timesteps x 4 stages, grid.sync
// between stages (replaces 95 dispatch boundaries). 157 blocks co-resident
// (55.5KB LDS, ~165 VGPR -> 1 block/CU).
__global__ __launch_bounds__(512, 2) void k_mega(MegaArgs a) {
  cg::grid_group grid = cg::this_grid();
  __shared__ float smemF[PB * 8 + FP * 33];
  for (int t = 0; t < 2 * TT; ++t) {
    const bool enc = t < TT;
    const float* Wg = enc ? a.eWg : a.dWg;
    const float* Bg = enc ? a.eBg : a.dBg;
    const float* Wc = enc ? a.eWc : a.dWc;
    const float* Bc = enc ? a.eBc : a.dBc;
    int mode, tn = 0, ds = 0;
    if (t < TT - 1) { mode = 0; tn = t + 1; }
    else if (t == TT - 1) { mode = 1; }
    else { mode = 2; ds = t - TT; }

    // stage 1: x1_g = A @ xh_g
    gemm_stage<0>(smemF, a.adjb, a.xhGb, a.x1f, a.x1b,
                  nullptr, nullptr, nullptr, nullptr, nullptr, nullptr,
                  nullptr, nullptr, nullptr, nullptr, nullptr, nullptr, 0, 0, 0);
    grid.sync();
    // stage 2: x2_g = A @ x1_g ; gate epilogue -> xh_c, u
    gemm_stage<1>(smemF, a.adjb, a.x1b, nullptr, nullptr,
                  a.xhGf, a.x1f, Wg, Bg, a.hT, a.uT, a.xhCf, a.xhCb,
                  nullptr, nullptr, nullptr, nullptr, 0, 0, 0);
    grid.sync();
    // stage 3: x1_c = A @ xh_c
    gemm_stage<0>(smemF, a.adjb, a.xhCb, a.x1f, a.x1b,
                  nullptr, nullptr, nullptr, nullptr, nullptr, nullptr,
                  nullptr, nullptr, nullptr, nullptr, nullptr, nullptr, 0, 0, 0);
    grid.sync();
    // stage 4: x2_c = A @ x1_c ; candidate epilogue -> h, next xh_g (+ proj)
    gemm_stage<2>(smemF, a.adjb, a.x1b, nullptr, nullptr,
                  a.xhCf, a.x1f, Wc, Bc, a.hT, a.uT, a.xhGf, a.xhGb,
                  a.inp, a.Wp, a.bp, a.dout, mode, tn, ds);
    grid.sync();
  }
}

// Fallback (workspace too small for adjb): fp32-A on-the-fly cast, 4 dispatches
// per timestep (R5-equivalent fp32 path).
template <int EPI>
__global__ __launch_bounds__(512, 2) void k_gemm_f(
    const float* __restrict__ adjf,
    const unsigned short* __restrict__ rhs,
    float* __restrict__ outF, unsigned short* __restrict__ outB,
    const float* __restrict__ s0F, const float* __restrict__ s1F,
    const float* __restrict__ W, const float* __restrict__ bias,
    float* __restrict__ hT, float* __restrict__ uT,
    float* __restrict__ xoF, unsigned short* __restrict__ xoB,
    const float* __restrict__ inp, const float* __restrict__ Wp,
    const float* __restrict__ bp, float* __restrict__ dout,
    int mode, int tnext, int dstep) {
  constexpr int WC = (EPI == 1) ? 64 : 32;
  __shared__ float smemF[PB * 8 + FP * 33];
  float* Pv = smemF;
  float* x2s = smemF + PB * 8;
  float* Ws = smemF;

  const int tid = threadIdx.x;
  const int wave = tid >> 6;
  const int lane = tid & 63;
  const int m = lane & 15;
  const int q = lane >> 4;
  const int nodeBase = blockIdx.x * BNODE;

  f32x4 acc[2][3] = {};
  for (int i = 0; i < CPW; ++i) {
    const int ch = wave * CPW + i;
    const int k0 = ch * KC;
    short8 cx[12];
    const unsigned short* xb = rhs + (size_t)ch * CHE + lane * 8;
#pragma unroll
    for (int t3 = 0; t3 < 3; ++t3)
#pragma unroll
      for (int ks = 0; ks < 4; ++ks)
        cx[t3 * 4 + ks] = *(const short8*)(xb + t3 * 2048 + ks * 512);
#pragma unroll
    for (int h = 0; h < 2; ++h) {
      int gnh = nodeBase + h * 16 + m;
      const float* a0 = adjf + (size_t)((gnh < NN) ? gnh : NN - 1) * NN;
#pragma unroll
      for (int ks = 0; ks < 4; ++ks) {
        int kb = k0 + ks * 32 + q * 8;
        union { short8 s; unsigned short u[8]; } p0;
        if (kb + 8 <= NN) {
          float4 x0 = *(const float4*)(a0 + kb);
          float4 x1 = *(const float4*)(a0 + kb + 4);
          p0.u[0] = f2bf(x0.x); p0.u[1] = f2bf(x0.y); p0.u[2] = f2bf(x0.z); p0.u[3] = f2bf(x0.w);
          p0.u[4] = f2bf(x1.x); p0.u[5] = f2bf(x1.y); p0.u[6] = f2bf(x1.z); p0.u[7] = f2bf(x1.w);
        } else {
          for (int j = 0; j < 8; ++j) {
            int k = kb + j;
            p0.u[j] = (k < NN) ? f2bf(a0[k]) : (unsigned short)0;
          }
        }
        acc[h][0] = __builtin_amdgcn_mfma_f32_16x16x32_bf16(cx[ks], p0.s, acc[h][0], 0, 0, 0);
        acc[h][1] = __builtin_amdgcn_mfma_f32_16x16x32_bf16(cx[4 + ks], p0.s, acc[h][1], 0, 0, 0);
        acc[h][2] = __builtin_amdgcn_mfma_f32_16x16x32_bf16(cx[8 + ks], p0.s, acc[h][2], 0, 0, 0);
      }
    }
  }

#pragma unroll
  for (int h = 0; h < 2; ++h)
#pragma unroll
    for (int t3 = 0; t3 < 3; ++t3)
#pragma unroll
      for (int r = 0; r < 4; ++r)
        Pv[wave * PB + (t3 * 16 + q * 4 + r) * BNODE + h * 16 + m] = acc[h][t3][r];
  __syncthreads();

  if constexpr (EPI == 0) {
    for (int e = tid; e < PB; e += 512) {
      int f = e >> 5, n = e & 31;
      float v = 0.f;
#pragma unroll
      for (int w = 0; w < 8; ++w) v += Pv[w * PB + e];
      int gn2 = nodeBase + n;
      if (gn2 >= NN) v = 0.f;
      outF[(size_t)f * NP + gn2] = v;
      outB[flatXF(f, gn2)] = f2bf(v);
    }
  } else {
    for (int e = tid; e < PB; e += 512) {
      int f = e >> 5, n = e & 31;
      float v = 0.f;
#pragma unroll
      for (int w = 0; w < 8; ++w) v += Pv[w * PB + e];
      x2s[f * 33 + n] = v;
    }
    __syncthreads();
    for (int i = tid; i < DN * WC; i += 512) Ws[i] = W[i];
    __syncthreads();
    const int nl = tid & 15;
    const int cg = tid >> 4;
    float hwv[2];
#pragma unroll
    for (int nh = 0; nh < 2; ++nh) {
      const int nl2 = nh * 16 + nl;
      const int gn2 = nodeBase + nl2;
      const bool valid = gn2 < NN;
      const int gnc = valid ? gn2 : NN - 1;
      if constexpr (EPI == 1) {
        float a0 = bias[cg], a1 = bias[cg + 32];
        for (int f = 0; f < FR; ++f) {
          float fe = s0F[(size_t)f * NP + gnc];
          a0 += fe * Ws[f * WC + cg]; a1 += fe * Ws[f * WC + cg + 32];
        }
        for (int f = 0; f < FR; ++f) {
          float fe = s1F[(size_t)f * NP + gnc];
          a0 += fe * Ws[(FR + f) * WC + cg]; a1 += fe * Ws[(FR + f) * WC + cg + 32];
        }
        for (int f = 0; f < FR; ++f) {
          float fe = x2s[f * 33 + nl2];
          a0 += fe * Ws[(2 * FR + f) * WC + cg]; a1 += fe * Ws[(2 * FR + f) * WC + cg + 32];
        }
        float r = 1.f / (1.f + expf(-a0));
        float hv = hT[(size_t)cg * NP + gnc];
        float xc = valid ? r * hv : 0.f;
        xoF[(size_t)(1 + cg) * NP + gn2] = xc;
        xoB[flatXF(1 + cg, gn2)] = f2bf(xc);
        float u = 1.f / (1.f + expf(-a1));
        uT[(size_t)cg * NP + gn2] = valid ? u : 0.f;
        hwv[nh] = 0.f;
      } else {
        float a0 = bias[cg];
        for (int f = 0; f < FR; ++f) a0 += s0F[(size_t)f * NP + gnc] * Ws[f * WC + cg];
        for (int f = 0; f < FR; ++f) a0 += s1F[(size_t)f * NP + gnc] * Ws[(FR + f) * WC + cg];
        for (int f = 0; f < FR; ++f) a0 += x2s[f * 33 + nl2] * Ws[(2 * FR + f) * WC + cg];
        float c = tanhf(a0);
        float u = uT[(size_t)cg * NP + gnc];
        float h0 = hT[(size_t)cg * NP + gnc];
        float hn = u * h0 + (1.f - u) * c;
        float hw = valid ? hn : 0.f;
        hwv[nh] = hw;
        hT[(size_t)cg * NP + gn2] = hw;
        xoF[(size_t)(1 + cg) * NP + gn2] = hw;
        xoB[flatXF(1 + cg, gn2)] = f2bf(hw);
      }
    }
    if constexpr (EPI == 1) {
      if (tid < BNODE) {
        int g3 = nodeBase + tid;
        float v0 = s0F[g3];
        xoF[g3] = v0;
        xoB[flatXF(0, g3)] = f2bf(v0);
      }
    } else {
      __syncthreads();
      x2s[cg * 33 + nl] = hwv[0];
      x2s[cg * 33 + 16 + nl] = hwv[1];
      __syncthreads();
      if (tid < BNODE) {
        int g3 = nodeBase + tid;
        bool v3 = g3 < NN;
        float x0 = 0.f;
        if (mode == 0) {
          x0 = v3 ? inp[(size_t)g3 * TT + tnext] : 0.f;
        } else if (mode == 2) {
          float p = bp[0];
          for (int j = 0; j < UU; ++j) p += x2s[j * 33 + tid] * Wp[j];
          if (v3) dout[(size_t)g3 * TT + dstep] = p;
          x0 = v3 ? p : 0.f;
        }
        xoF[g3] = x0;
        xoB[flatXF(0, g3)] = f2bf(x0);
      }
    }
  }
}

extern "C" void kernel_launch(void* const* d_in, const int* in_sizes, int n_in,
                              void* d_out, int out_size, void* d_ws, size_t ws_size,
                              hipStream_t stream) {
  const float* inputs = (const float*)d_in[0];
  const float* adj = (const float*)d_in[2];
  const float* eWg = (const float*)d_in[3];
  const float* eBg = (const float*)d_in[4];
  const float* eWc = (const float*)d_in[5];
  const float* eBc = (const float*)d_in[6];
  const float* dWg = (const float*)d_in[7];
  const float* dBg = (const float*)d_in[8];
  const float* dWc = (const float*)d_in[9];
  const float* dBc = (const float*)d_in[10];
  const float* Wp = (const float*)d_in[11];
  const float* bp = (const float*)d_in[12];
  float* dout = (float*)d_out;

  char* ws = (char*)d_ws;
  size_t o = 0;
  float* xhGf = (float*)(ws + o); o += (size_t)FP * NP * 4;
  unsigned short* xhGb = (unsigned short*)(ws + o); o += (size_t)FP * NP * 2;
  float* xhCf = (float*)(ws + o); o += (size_t)FP * NP * 4;
  unsigned short* xhCb = (unsigned short*)(ws + o); o += (size_t)FP * NP * 2;
  float* x1f = (float*)(ws + o); o += (size_t)FP * NP * 4;
  unsigned short* x1b = (unsigned short*)(ws + o); o += (size_t)FP * NP * 2;
  float* hT = (float*)(ws + o); o += (size_t)UU * NP * 4;
  float* uT = (float*)(ws + o); o += (size_t)UU * NP * 4;
  size_t small = o;
  unsigned short* adjb = (unsigned short*)(ws + o);
  size_t need = o + (size_t)NP * NP * 2;
  bool usebf = ws_size >= need;

  k_zero<<<(int)((small / 16 + 255) / 256), 256, 0, stream>>>((uint4*)ws, (int)(small / 16));
  if (usebf) k_cast2<<<(NP / 8) * NP / 256, 256, 0, stream>>>(adj, adjb);
  k_initx0<<<NP / 256, 256, 0, stream>>>(inputs, xhGf, xhGb);

  if (usebf) {
    MegaArgs ha;
    ha.adjb = adjb;
    ha.xhGb = xhGb; ha.xhGf = xhGf;
    ha.xhCb = xhCb; ha.xhCf = xhCf;
    ha.x1b = x1b;   ha.x1f = x1f;
    ha.hT = hT;     ha.uT = uT;
    ha.eWg = eWg; ha.eBg = eBg; ha.eWc = eWc; ha.eBc = eBc;
    ha.dWg = dWg; ha.dBg = dBg; ha.dWc = dWc; ha.dBc = dBc;
    ha.Wp = Wp; ha.bp = bp;
    ha.inp = inputs; ha.dout = dout;
    void* kargs[] = {&ha};
    hipLaunchCooperativeKernel((void*)k_mega, dim3(GRID_MM), dim3(512),
                               kargs, 0, stream);
  } else {
    for (int t = 0; t < 2 * TT; ++t) {
      bool enc = t < TT;
      const float* Wg = enc ? eWg : dWg;
      const float* Bg = enc ? eBg : dBg;
      const float* Wc = enc ? eWc : dWc;
      const float* Bc = enc ? eBc : dBc;
      int mode, tn = 0, ds = 0;
      if (t < TT - 1) { mode = 0; tn = t + 1; }
      else if (t == TT - 1) { mode = 1; }
      else { mode = 2; ds = t - TT; }

      k_gemm_f<0><<<GRID_MM, 512, 0, stream>>>(
          adj, xhGb, x1f, x1b,
          nullptr, nullptr, nullptr, nullptr, nullptr, nullptr,
          nullptr, nullptr, nullptr, nullptr, nullptr, nullptr, 0, 0, 0);
      k_gemm_f<1><<<GRID_MM, 512, 0, stream>>>(
          adj, x1b, nullptr, nullptr,
          xhGf, x1f, Wg, Bg, hT, uT, xhCf, xhCb,
          nullptr, nullptr, nullptr, nullptr, 0, 0, 0);
      k_gemm_f<0><<<GRID_MM, 512, 0, stream>>>(
          adj, xhCb, x1f, x1b,
          nullptr, nullptr, nullptr, nullptr, nullptr, nullptr,
          nullptr, nullptr, nullptr, nullptr, nullptr, nullptr, 0, 0, 0);
      k_gemm_f<2><<<GRID_MM, 512, 0, stream>>>(
          adj, x1b, nullptr, nullptr,
          xhCf, x1f, Wc, Bc, hT, uT, xhGf, xhGb,
          inputs, Wp, bp, dout, mode, tn, ds);
    }
  }
}

// Round 12
// 6408.613 us; speedup vs baseline: 1.0066x; 1.0066x over previous
//
#include <hip/hip_runtime.h>
#include <hip/hip_cooperative_groups.h>
#include <type_traits>

namespace cg = cooperative_groups;

constexpr int NN = 5000;   // nodes
constexpr int NP = 5120;   // padded nodes / K
constexpr int TT = 12;     // enc/dec length
constexpr int UU = 32;     // rnn units
constexpr int FP = 48;     // padded feature rows
constexpr int FR = 33;     // real feature rows (IN+U)
constexpr int DN = 99;     // DIN
constexpr int BN = 16;     // nodes per A-fragment tile
constexpr int BNODE = 32;  // nodes per block (2 fragment tiles)
constexpr int KC = 128;    // K chunk
constexpr int NKC = NP / KC;                 // 40
constexpr int CPW = NKC / 8;                 // 5 chunks per wave (8-way K split)
constexpr int GRID_MM = (NN + BNODE - 1) / BNODE;  // 157
constexpr int CHE = FP * KC;                 // 6144 elements per chunk (frag layout)
constexpr int ACH = BN * KC;                 // 2048 elements per (node-tile, chunk) A frag
constexpr int PB = FP * BNODE;               // 1536 partial elems per wave

typedef __attribute__((ext_vector_type(8))) short short8;
typedef __attribute__((ext_vector_type(4))) float f32x4;

__device__ __forceinline__ unsigned short f2bf(float x) {
  union { float f; unsigned u; } c; c.f = x;
  return (unsigned short)((c.u + 0x7FFFu + ((c.u >> 16) & 1u)) >> 16);
}

// MFMA A-fragment layout for X^T: element (f, node-as-K) -> flat index such
// that a wave's 16B load at base+lane*16 is fully coalesced.
__device__ __forceinline__ int flatXF(int f, int node) {
  int chunk = node >> 7;
  int ks = (node >> 5) & 3;
  int q = (node >> 3) & 3;
  int j = node & 7;
  int t3 = f >> 4;
  int m = f & 15;
  return chunk * CHE + t3 * 2048 + ks * 512 + (m + 16 * q) * 8 + j;
}

__global__ void k_zero(uint4* __restrict__ p, int n) {
  int i = blockIdx.x * 256 + threadIdx.x;
  if (i < n) p[i] = make_uint4(0u, 0u, 0u, 0u);
}

// Output-centric A swizzle: consecutive threads write consecutive 16B of the
// fragment-ordered adjb (perfect write stream).
__global__ void k_cast2(const float* __restrict__ adj, unsigned short* __restrict__ adjb) {
  int gid = blockIdx.x * 256 + threadIdx.x;  // < NP*NP/8
  int tile = gid >> 8;                       // (nt*NKC + c)
  int r2 = gid & 255;
  int nt = tile / NKC, c = tile - nt * NKC;
  int ks = r2 >> 6;
  int qm = r2 & 63;
  int q = qm >> 4, m = qm & 15;
  int n = nt * 16 + m;
  int k = c * 128 + ks * 32 + q * 8;
  union { short8 s; unsigned short u[8]; } o;
  if (n < NN && k < NN) {
    const f32x4* a = reinterpret_cast<const f32x4*>(adj + (size_t)n * NN + k);
    f32x4 x0 = __builtin_nontemporal_load(a);
    f32x4 x1 = __builtin_nontemporal_load(a + 1);
    o.u[0] = f2bf(x0.x); o.u[1] = f2bf(x0.y); o.u[2] = f2bf(x0.z); o.u[3] = f2bf(x0.w);
    o.u[4] = f2bf(x1.x); o.u[5] = f2bf(x1.y); o.u[6] = f2bf(x1.z); o.u[7] = f2bf(x1.w);
  } else {
    o.u[0] = 0; o.u[1] = 0; o.u[2] = 0; o.u[3] = 0;
    o.u[4] = 0; o.u[5] = 0; o.u[6] = 0; o.u[7] = 0;
  }
  *reinterpret_cast<short8*>(adjb + (size_t)gid * 8) = o.s;
}

__global__ void k_initx0(const float* __restrict__ in, float* __restrict__ xf,
                         unsigned short* __restrict__ xb) {
  int n = blockIdx.x * 256 + threadIdx.x;
  if (n >= NP) return;
  float v = (n < NN) ? in[(size_t)n * TT] : 0.f;
  xf[n] = v;
  xb[flatXF(0, n)] = f2bf(v);
}

// One GEMM stage (R5 structure, USEBF hardwired): C^T[f][node] over this
// block's 32 nodes. 8 waves; wave w owns K slice [w*640,+640); A dbuf'd,
// X loads issued first each chunk. COMPILE-TIME unrolled CPW loop (R9
// lesson). No early returns (cooperative grid.sync follows each call).
template <int EPI>
__device__ __forceinline__ void gemm_stage(
    float* __restrict__ smemF,
    const unsigned short* __restrict__ adjb,
    const unsigned short* __restrict__ rhs,
    float* __restrict__ outF, unsigned short* __restrict__ outB,
    const float* __restrict__ s0F, const float* __restrict__ s1F,
    const float* __restrict__ W, const float* __restrict__ bias,
    float* __restrict__ hT, float* __restrict__ uT,
    float* __restrict__ xoF, unsigned short* __restrict__ xoB,
    const float* __restrict__ inp, const float* __restrict__ Wp,
    const float* __restrict__ bp, float* __restrict__ dout,
    int mode, int tnext, int dstep) {
  constexpr int WC = (EPI == 1) ? 64 : 32;
  float* Pv = smemF;
  float* x2s = smemF + PB * 8;
  float* Ws = smemF;  // overlays Pv after reduce

  const int tid = threadIdx.x;
  const int wave = tid >> 6;
  const int lane = tid & 63;
  const int m = lane & 15;
  const int q = lane >> 4;
  const int nodeBase = blockIdx.x * BNODE;

  f32x4 acc[2][3] = {};
  short8 aCur[2][4], aNxt[2][4];

  const unsigned short* aB0 =
      adjb + (size_t)(2 * blockIdx.x) * NKC * ACH + lane * 8;
  const unsigned short* aB1 =
      adjb + (size_t)(2 * blockIdx.x + 1) * NKC * ACH + lane * 8;

  auto loadA = [&](int i, short8 (&b)[2][4]) {
    const int ch = wave * CPW + i;
    const unsigned short* a0 = aB0 + (size_t)ch * ACH;
    const unsigned short* a1 = aB1 + (size_t)ch * ACH;
#pragma unroll
    for (int ks = 0; ks < 4; ++ks) {
      b[0][ks] = *reinterpret_cast<const short8*>(a0 + ks * 512);
      b[1][ks] = *reinterpret_cast<const short8*>(a1 + ks * 512);
    }
  };

  loadA(0, aCur);
#pragma unroll
  for (int i = 0; i < CPW; ++i) {
    const int ch = wave * CPW + i;
    short8 cx[12];
    const unsigned short* xb = rhs + (size_t)ch * CHE + lane * 8;
    // X loads first (older in vmcnt order)...
#pragma unroll
    for (int t3 = 0; t3 < 3; ++t3)
#pragma unroll
      for (int ks = 0; ks < 4; ++ks)
        cx[t3 * 4 + ks] = *(const short8*)(xb + t3 * 2048 + ks * 512);
    // ...then the A prefetch: waiting for cx leaves these in flight.
    if (i + 1 < CPW) loadA(i + 1, aNxt);
#pragma unroll
    for (int ks = 0; ks < 4; ++ks) {
#pragma unroll
      for (int h = 0; h < 2; ++h) {
        acc[h][0] = __builtin_amdgcn_mfma_f32_16x16x32_bf16(cx[ks], aCur[h][ks], acc[h][0], 0, 0, 0);
        acc[h][1] = __builtin_amdgcn_mfma_f32_16x16x32_bf16(cx[4 + ks], aCur[h][ks], acc[h][1], 0, 0, 0);
        acc[h][2] = __builtin_amdgcn_mfma_f32_16x16x32_bf16(cx[8 + ks], aCur[h][ks], acc[h][2], 0, 0, 0);
      }
    }
#pragma unroll
    for (int h = 0; h < 2; ++h)
#pragma unroll
      for (int ks = 0; ks < 4; ++ks) aCur[h][ks] = aNxt[h][ks];
  }

#pragma unroll
  for (int h = 0; h < 2; ++h)
#pragma unroll
    for (int t3 = 0; t3 < 3; ++t3)
#pragma unroll
      for (int r = 0; r < 4; ++r)
        Pv[wave * PB + (t3 * 16 + q * 4 + r) * BNODE + h * 16 + m] = acc[h][t3][r];
  __syncthreads();

  if constexpr (EPI == 0) {
    for (int e = tid; e < PB; e += 512) {
      int f = e >> 5, n = e & 31;
      float v = 0.f;
#pragma unroll
      for (int w = 0; w < 8; ++w) v += Pv[w * PB + e];
      int gn2 = nodeBase + n;
      if (gn2 >= NN) v = 0.f;
      outF[(size_t)f * NP + gn2] = v;
      outB[flatXF(f, gn2)] = f2bf(v);
    }
    __syncthreads();  // Pv reads done before next stage reuses smem
  } else {
    for (int e = tid; e < PB; e += 512) {
      int f = e >> 5, n = e & 31;
      float v = 0.f;
#pragma unroll
      for (int w = 0; w < 8; ++w) v += Pv[w * PB + e];
      x2s[f * 33 + n] = v;
    }
    __syncthreads();
    // Pv is dead; overlay epilogue weights
    for (int i = tid; i < DN * WC; i += 512) Ws[i] = W[i];
    __syncthreads();
    const int nl = tid & 15;
    const int cg = tid >> 4;  // 0..31
    float hwv[2];
#pragma unroll
    for (int nh = 0; nh < 2; ++nh) {
      const int nl2 = nh * 16 + nl;
      const int gn2 = nodeBase + nl2;
      const bool valid = gn2 < NN;
      const int gnc = valid ? gn2 : NN - 1;
      if constexpr (EPI == 1) {
        float a0 = bias[cg], a1 = bias[cg + 32];
        for (int f = 0; f < FR; ++f) {
          float fe = s0F[(size_t)f * NP + gnc];
          a0 += fe * Ws[f * WC + cg]; a1 += fe * Ws[f * WC + cg + 32];
        }
        for (int f = 0; f < FR; ++f) {
          float fe = s1F[(size_t)f * NP + gnc];
          a0 += fe * Ws[(FR + f) * WC + cg]; a1 += fe * Ws[(FR + f) * WC + cg + 32];
        }
        for (int f = 0; f < FR; ++f) {
          float fe = x2s[f * 33 + nl2];
          a0 += fe * Ws[(2 * FR + f) * WC + cg]; a1 += fe * Ws[(2 * FR + f) * WC + cg + 32];
        }
        float r = 1.f / (1.f + expf(-a0));          // r gate (cols 0..31)
        float hv = hT[(size_t)cg * NP + gnc];
        float xc = valid ? r * hv : 0.f;
        xoF[(size_t)(1 + cg) * NP + gn2] = xc;
        xoB[flatXF(1 + cg, gn2)] = f2bf(xc);
        float u = 1.f / (1.f + expf(-a1));          // u gate (cols 32..63)
        uT[(size_t)cg * NP + gn2] = valid ? u : 0.f;
        hwv[nh] = 0.f;
      } else {
        float a0 = bias[cg];
        for (int f = 0; f < FR; ++f) a0 += s0F[(size_t)f * NP + gnc] * Ws[f * WC + cg];
        for (int f = 0; f < FR; ++f) a0 += s1F[(size_t)f * NP + gnc] * Ws[(FR + f) * WC + cg];
        for (int f = 0; f < FR; ++f) a0 += x2s[f * 33 + nl2] * Ws[(2 * FR + f) * WC + cg];
        float c = tanhf(a0);
        float u = uT[(size_t)cg * NP + gnc];
        float h0 = hT[(size_t)cg * NP + gnc];
        float hn = u * h0 + (1.f - u) * c;
        float hw = valid ? hn : 0.f;
        hwv[nh] = hw;
        hT[(size_t)cg * NP + gn2] = hw;
        xoF[(size_t)(1 + cg) * NP + gn2] = hw;
        xoB[flatXF(1 + cg, gn2)] = f2bf(hw);
      }
    }
    if constexpr (EPI == 1) {
      if (tid < BNODE) {
        int g3 = nodeBase + tid;
        float v0 = s0F[g3];
        xoF[g3] = v0;
        xoB[flatXF(0, g3)] = f2bf(v0);
      }
      __syncthreads();  // x2s/Ws reads done before next stage reuses smem
    } else {
      __syncthreads();                 // all x2s reads done
      x2s[cg * 33 + nl] = hwv[0];      // reuse as h scratch [col][node]
      x2s[cg * 33 + 16 + nl] = hwv[1];
      __syncthreads();
      if (tid < BNODE) {
        int g3 = nodeBase + tid;
        bool v3 = g3 < NN;
        float x0 = 0.f;
        if (mode == 0) {
          x0 = v3 ? inp[(size_t)g3 * TT + tnext] : 0.f;
        } else if (mode == 2) {
          float p = bp[0];
          for (int j = 0; j < UU; ++j) p += x2s[j * 33 + tid] * Wp[j];
          if (v3) dout[(size_t)g3 * TT + dstep] = p;
          x0 = v3 ? p : 0.f;
        }
        xoF[g3] = x0;
        xoB[flatXF(0, g3)] = f2bf(x0);
      }
      __syncthreads();  // x2s reads done before next stage reuses smem
    }
  }
}

struct MegaArgs {
  const unsigned short* adjb;
  unsigned short* xhGb; float* xhGf;
  unsigned short* xhCb; float* xhCf;
  unsigned short* x1b;  float* x1f;
  float* hT; float* uT;
  const float* eWg; const float* eBg; const float* eWc; const float* eBc;
  const float* dWg; const float* dBg; const float* dWc; const float* dBc;
  const float* Wp; const float* bp;
  const float* inp; float* dout;
};

// Persistent cooperative megakernel: all 24 timesteps x 4 stages, grid.sync
// between stages (replaces 95 dispatch boundaries). 157 blocks co-resident.
// waves_per_eu(2,2): pin occupancy to exactly 2 waves/EU (1 block/CU) so the
// register allocator gets the full 256-VGPR budget and keeps the R5 schedule.
// R11 lesson: launch_bounds(512,2) alone let the allocator target 128 VGPR
// (4 waves/EU) and serialize/spill the K-loop -> 6387us, MfmaUtil 1.5%.
__global__ __attribute__((amdgpu_flat_work_group_size(512, 512)))
__attribute__((amdgpu_waves_per_eu(2, 2))) void k_mega(MegaArgs a) {
  cg::grid_group grid = cg::this_grid();
  __shared__ float smemF[PB * 8 + FP * 33];
  for (int t = 0; t < 2 * TT; ++t) {
    const bool enc = t < TT;
    const float* Wg = enc ? a.eWg : a.dWg;
    const float* Bg = enc ? a.eBg : a.dBg;
    const float* Wc = enc ? a.eWc : a.dWc;
    const float* Bc = enc ? a.eBc : a.dBc;
    int mode, tn = 0, ds = 0;
    if (t < TT - 1) { mode = 0; tn = t + 1; }
    else if (t == TT - 1) { mode = 1; }
    else { mode = 2; ds = t - TT; }

    // stage 1: x1_g = A @ xh_g
    gemm_stage<0>(smemF, a.adjb, a.xhGb, a.x1f, a.x1b,
                  nullptr, nullptr, nullptr, nullptr, nullptr, nullptr,
                  nullptr, nullptr, nullptr, nullptr, nullptr, nullptr, 0, 0, 0);
    grid.sync();
    // stage 2: x2_g = A @ x1_g ; gate epilogue -> xh_c, u
    gemm_stage<1>(smemF, a.adjb, a.x1b, nullptr, nullptr,
                  a.xhGf, a.x1f, Wg, Bg, a.hT, a.uT, a.xhCf, a.xhCb,
                  nullptr, nullptr, nullptr, nullptr, 0, 0, 0);
    grid.sync();
    // stage 3: x1_c = A @ xh_c
    gemm_stage<0>(smemF, a.adjb, a.xhCb, a.x1f, a.x1b,
                  nullptr, nullptr, nullptr, nullptr, nullptr, nullptr,
                  nullptr, nullptr, nullptr, nullptr, nullptr, nullptr, 0, 0, 0);
    grid.sync();
    // stage 4: x2_c = A @ x1_c ; candidate epilogue -> h, next xh_g (+ proj)
    gemm_stage<2>(smemF, a.adjb, a.x1b, nullptr, nullptr,
                  a.xhCf, a.x1f, Wc, Bc, a.hT, a.uT, a.xhGf, a.xhGb,
                  a.inp, a.Wp, a.bp, a.dout, mode, tn, ds);
    grid.sync();
  }
}

// Fallback (workspace too small for adjb): fp32-A on-the-fly cast, 4 dispatches
// per timestep (R5-equivalent fp32 path).
template <int EPI>
__global__ __launch_bounds__(512, 2) void k_gemm_f(
    const float* __restrict__ adjf,
    const unsigned short* __restrict__ rhs,
    float* __restrict__ outF, unsigned short* __restrict__ outB,
    const float* __restrict__ s0F, const float* __restrict__ s1F,
    const float* __restrict__ W, const float* __restrict__ bias,
    float* __restrict__ hT, float* __restrict__ uT,
    float* __restrict__ xoF, unsigned short* __restrict__ xoB,
    const float* __restrict__ inp, const float* __restrict__ Wp,
    const float* __restrict__ bp, float* __restrict__ dout,
    int mode, int tnext, int dstep) {
  constexpr int WC = (EPI == 1) ? 64 : 32;
  __shared__ float smemF[PB * 8 + FP * 33];
  float* Pv = smemF;
  float* x2s = smemF + PB * 8;
  float* Ws = smemF;

  const int tid = threadIdx.x;
  const int wave = tid >> 6;
  const int lane = tid & 63;
  const int m = lane & 15;
  const int q = lane >> 4;
  const int nodeBase = blockIdx.x * BNODE;

  f32x4 acc[2][3] = {};
  for (int i = 0; i < CPW; ++i) {
    const int ch = wave * CPW + i;
    const int k0 = ch * KC;
    short8 cx[12];
    const unsigned short* xb = rhs + (size_t)ch * CHE + lane * 8;
#pragma unroll
    for (int t3 = 0; t3 < 3; ++t3)
#pragma unroll
      for (int ks = 0; ks < 4; ++ks)
        cx[t3 * 4 + ks] = *(const short8*)(xb + t3 * 2048 + ks * 512);
#pragma unroll
    for (int h = 0; h < 2; ++h) {
      int gnh = nodeBase + h * 16 + m;
      const float* a0 = adjf + (size_t)((gnh < NN) ? gnh : NN - 1) * NN;
#pragma unroll
      for (int ks = 0; ks < 4; ++ks) {
        int kb = k0 + ks * 32 + q * 8;
        union { short8 s; unsigned short u[8]; } p0;
        if (kb + 8 <= NN) {
          float4 x0 = *(const float4*)(a0 + kb);
          float4 x1 = *(const float4*)(a0 + kb + 4);
          p0.u[0] = f2bf(x0.x); p0.u[1] = f2bf(x0.y); p0.u[2] = f2bf(x0.z); p0.u[3] = f2bf(x0.w);
          p0.u[4] = f2bf(x1.x); p0.u[5] = f2bf(x1.y); p0.u[6] = f2bf(x1.z); p0.u[7] = f2bf(x1.w);
        } else {
          for (int j = 0; j < 8; ++j) {
            int k = kb + j;
            p0.u[j] = (k < NN) ? f2bf(a0[k]) : (unsigned short)0;
          }
        }
        acc[h][0] = __builtin_amdgcn_mfma_f32_16x16x32_bf16(cx[ks], p0.s, acc[h][0], 0, 0, 0);
        acc[h][1] = __builtin_amdgcn_mfma_f32_16x16x32_bf16(cx[4 + ks], p0.s, acc[h][1], 0, 0, 0);
        acc[h][2] = __builtin_amdgcn_mfma_f32_16x16x32_bf16(cx[8 + ks], p0.s, acc[h][2], 0, 0, 0);
      }
    }
  }

#pragma unroll
  for (int h = 0; h < 2; ++h)
#pragma unroll
    for (int t3 = 0; t3 < 3; ++t3)
#pragma unroll
      for (int r = 0; r < 4; ++r)
        Pv[wave * PB + (t3 * 16 + q * 4 + r) * BNODE + h * 16 + m] = acc[h][t3][r];
  __syncthreads();

  if constexpr (EPI == 0) {
    for (int e = tid; e < PB; e += 512) {
      int f = e >> 5, n = e & 31;
      float v = 0.f;
#pragma unroll
      for (int w = 0; w < 8; ++w) v += Pv[w * PB + e];
      int gn2 = nodeBase + n;
      if (gn2 >= NN) v = 0.f;
      outF[(size_t)f * NP + gn2] = v;
      outB[flatXF(f, gn2)] = f2bf(v);
    }
  } else {
    for (int e = tid; e < PB; e += 512) {
      int f = e >> 5, n = e & 31;
      float v = 0.f;
#pragma unroll
      for (int w = 0; w < 8; ++w) v += Pv[w * PB + e];
      x2s[f * 33 + n] = v;
    }
    __syncthreads();
    for (int i = tid; i < DN * WC; i += 512) Ws[i] = W[i];
    __syncthreads();
    const int nl = tid & 15;
    const int cg = tid >> 4;
    float hwv[2];
#pragma unroll
    for (int nh = 0; nh < 2; ++nh) {
      const int nl2 = nh * 16 + nl;
      const int gn2 = nodeBase + nl2;
      const bool valid = gn2 < NN;
      const int gnc = valid ? gn2 : NN - 1;
      if constexpr (EPI == 1) {
        float a0 = bias[cg], a1 = bias[cg + 32];
        for (int f = 0; f < FR; ++f) {
          float fe = s0F[(size_t)f * NP + gnc];
          a0 += fe * Ws[f * WC + cg]; a1 += fe * Ws[f * WC + cg + 32];
        }
        for (int f = 0; f < FR; ++f) {
          float fe = s1F[(size_t)f * NP + gnc];
          a0 += fe * Ws[(FR + f) * WC + cg]; a1 += fe * Ws[(FR + f) * WC + cg + 32];
        }
        for (int f = 0; f < FR; ++f) {
          float fe = x2s[f * 33 + nl2];
          a0 += fe * Ws[(2 * FR + f) * WC + cg]; a1 += fe * Ws[(2 * FR + f) * WC + cg + 32];
        }
        float r = 1.f / (1.f + expf(-a0));
        float hv = hT[(size_t)cg * NP + gnc];
        float xc = valid ? r * hv : 0.f;
        xoF[(size_t)(1 + cg) * NP + gn2] = xc;
        xoB[flatXF(1 + cg, gn2)] = f2bf(xc);
        float u = 1.f / (1.f + expf(-a1));
        uT[(size_t)cg * NP + gn2] = valid ? u : 0.f;
        hwv[nh] = 0.f;
      } else {
        float a0 = bias[cg];
        for (int f = 0; f < FR; ++f) a0 += s0F[(size_t)f * NP + gnc] * Ws[f * WC + cg];
        for (int f = 0; f < FR; ++f) a0 += s1F[(size_t)f * NP + gnc] * Ws[(FR + f) * WC + cg];
        for (int f = 0; f < FR; ++f) a0 += x2s[f * 33 + nl2] * Ws[(2 * FR + f) * WC + cg];
        float c = tanhf(a0);
        float u = uT[(size_t)cg * NP + gnc];
        float h0 = hT[(size_t)cg * NP + gnc];
        float hn = u * h0 + (1.f - u) * c;
        float hw = valid ? hn : 0.f;
        hwv[nh] = hw;
        hT[(size_t)cg * NP + gn2] = hw;
        xoF[(size_t)(1 + cg) * NP + gn2] = hw;
        xoB[flatXF(1 + cg, gn2)] = f2bf(hw);
      }
    }
    if constexpr (EPI == 1) {
      if (tid < BNODE) {
        int g3 = nodeBase + tid;
        float v0 = s0F[g3];
        xoF[g3] = v0;
        xoB[flatXF(0, g3)] = f2bf(v0);
      }
    } else {
      __syncthreads();
      x2s[cg * 33 + nl] = hwv[0];
      x2s[cg * 33 + 16 + nl] = hwv[1];
      __syncthreads();
      if (tid < BNODE) {
        int g3 = nodeBase + tid;
        bool v3 = g3 < NN;
        float x0 = 0.f;
        if (mode == 0) {
          x0 = v3 ? inp[(size_t)g3 * TT + tnext] : 0.f;
        } else if (mode == 2) {
          float p = bp[0];
          for (int j = 0; j < UU; ++j) p += x2s[j * 33 + tid] * Wp[j];
          if (v3) dout[(size_t)g3 * TT + dstep] = p;
          x0 = v3 ? p : 0.f;
        }
        xoF[g3] = x0;
        xoB[flatXF(0, g3)] = f2bf(x0);
      }
    }
  }
}

extern "C" void kernel_launch(void* const* d_in, const int* in_sizes, int n_in,
                              void* d_out, int out_size, void* d_ws, size_t ws_size,
                              hipStream_t stream) {
  const float* inputs = (const float*)d_in[0];
  const float* adj = (const float*)d_in[2];
  const float* eWg = (const float*)d_in[3];
  const float* eBg = (const float*)d_in[4];
  const float* eWc = (const float*)d_in[5];
  const float* eBc = (const float*)d_in[6];
  const float* dWg = (const float*)d_in[7];
  const float* dBg = (const float*)d_in[8];
  const float* dWc = (const float*)d_in[9];
  const float* dBc = (const float*)d_in[10];
  const float* Wp = (const float*)d_in[11];
  const float* bp = (const float*)d_in[12];
  float* dout = (float*)d_out;

  char* ws = (char*)d_ws;
  size_t o = 0;
  float* xhGf = (float*)(ws + o); o += (size_t)FP * NP * 4;
  unsigned short* xhGb = (unsigned short*)(ws + o); o += (size_t)FP * NP * 2;
  float* xhCf = (float*)(ws + o); o += (size_t)FP * NP * 4;
  unsigned short* xhCb = (unsigned short*)(ws + o); o += (size_t)FP * NP * 2;
  float* x1f = (float*)(ws + o); o += (size_t)FP * NP * 4;
  unsigned short* x1b = (unsigned short*)(ws + o); o += (size_t)FP * NP * 2;
  float* hT = (float*)(ws + o); o += (size_t)UU * NP * 4;
  float* uT = (float*)(ws + o); o += (size_t)UU * NP * 4;
  size_t small = o;
  unsigned short* adjb = (unsigned short*)(ws + o);
  size_t need = o + (size_t)NP * NP * 2;
  bool usebf = ws_size >= need;

  k_zero<<<(int)((small / 16 + 255) / 256), 256, 0, stream>>>((uint4*)ws, (int)(small / 16));
  if (usebf) k_cast2<<<(NP / 8) * NP / 256, 256, 0, stream>>>(adj, adjb);
  k_initx0<<<NP / 256, 256, 0, stream>>>(inputs, xhGf, xhGb);

  if (usebf) {
    MegaArgs ha;
    ha.adjb = adjb;
    ha.xhGb = xhGb; ha.xhGf = xhGf;
    ha.xhCb = xhCb; ha.xhCf = xhCf;
    ha.x1b = x1b;   ha.x1f = x1f;
    ha.hT = hT;     ha.uT = uT;
    ha.eWg = eWg; ha.eBg = eBg; ha.eWc = eWc; ha.eBc = eBc;
    ha.dWg = dWg; ha.dBg = dBg; ha.dWc = dWc; ha.dBc = dBc;
    ha.Wp = Wp; ha.bp = bp;
    ha.inp = inputs; ha.dout = dout;
    void* kargs[] = {&ha};
    hipLaunchCooperativeKernel((void*)k_mega, dim3(GRID_MM), dim3(512),
                               kargs, 0, stream);
  } else {
    for (int t = 0; t < 2 * TT; ++t) {
      bool enc = t < TT;
      const float* Wg = enc ? eWg : dWg;
      const float* Bg = enc ? eBg : dBg;
      const float* Wc = enc ? eWc : dWc;
      const float* Bc = enc ? eBc : dBc;
      int mode, tn = 0, ds = 0;
      if (t < TT - 1) { mode = 0; tn = t + 1; }
      else if (t == TT - 1) { mode = 1; }
      else { mode = 2; ds = t - TT; }

      k_gemm_f<0><<<GRID_MM, 512, 0, stream>>>(
          adj, xhGb, x1f, x1b,
          nullptr, nullptr, nullptr, nullptr, nullptr, nullptr,
          nullptr, nullptr, nullptr, nullptr, nullptr, nullptr, 0, 0, 0);
      k_gemm_f<1><<<GRID_MM, 512, 0, stream>>>(
          adj, x1b, nullptr, nullptr,
          xhGf, x1f, Wg, Bg, hT, uT, xhCf, xhCb,
          nullptr, nullptr, nullptr, nullptr, 0, 0, 0);
      k_gemm_f<0><<<GRID_MM, 512, 0, stream>>>(
          adj, xhCb, x1f, x1b,
          nullptr, nullptr, nullptr, nullptr, nullptr, nullptr,
          nullptr, nullptr, nullptr, nullptr, nullptr, nullptr, 0, 0, 0);
      k_gemm_f<2><<<GRID_MM, 512, 0, stream>>>(
          adj, x1b, nullptr, nullptr,
          xhCf, x1f, Wc, Bc, hT, uT, xhGf, xhGb,
          inputs, Wp, bp, dout, mode, tn, ds);
    }
  }
}

// Round 13
// 1793.995 us; speedup vs baseline: 3.5960x; 3.5723x over previous
//
#include <hip/hip_runtime.h>
#include <type_traits>

constexpr int NN = 5000;   // nodes
constexpr int NP = 5120;   // padded nodes / K
constexpr int TT = 12;     // enc/dec length
constexpr int UU = 32;     // rnn units
constexpr int FP = 48;     // padded feature rows
constexpr int FR = 33;     // real feature rows (IN+U)
constexpr int DN = 99;     // DIN
constexpr int BN = 16;     // nodes per A-fragment tile
constexpr int BNODE = 32;  // nodes per block (2 fragment tiles)
constexpr int KC = 128;    // K chunk
constexpr int NKC = NP / KC;                 // 40
constexpr int CPW = NKC / 8;                 // 5 chunks per wave (8-way K split)
constexpr int GRID_MM = (NN + BNODE - 1) / BNODE;  // 157
constexpr int CHE = FP * KC;                 // 6144 elements per chunk (frag layout)
constexpr int ACH = BN * KC;                 // 2048 elements per (node-tile, chunk) A frag
constexpr int PB = FP * BNODE;               // 1536 partial elems per wave

typedef __attribute__((ext_vector_type(8))) short short8;
typedef __attribute__((ext_vector_type(4))) float f32x4;

__device__ __forceinline__ unsigned short f2bf(float x) {
  union { float f; unsigned u; } c; c.f = x;
  return (unsigned short)((c.u + 0x7FFFu + ((c.u >> 16) & 1u)) >> 16);
}

// MFMA A-fragment layout for X^T: element (f, node-as-K) -> flat index such
// that a wave's 16B load at base+lane*16 is fully coalesced.
__device__ __forceinline__ int flatXF(int f, int node) {
  int chunk = node >> 7;
  int ks = (node >> 5) & 3;
  int q = (node >> 3) & 3;
  int j = node & 7;
  int t3 = f >> 4;
  int m = f & 15;
  return chunk * CHE + t3 * 2048 + ks * 512 + (m + 16 * q) * 8 + j;
}

__global__ void k_zero(uint4* __restrict__ p, int n) {
  int i = blockIdx.x * 256 + threadIdx.x;
  if (i < n) p[i] = make_uint4(0u, 0u, 0u, 0u);
}

// Output-centric A swizzle: consecutive threads write consecutive 16B of the
// fragment-ordered adjb (perfect write stream). Source reads are 32B chunks;
// lanes q=0..3 of the same row cover a contiguous 128B row segment.
__global__ void k_cast2(const float* __restrict__ adj, unsigned short* __restrict__ adjb) {
  int gid = blockIdx.x * 256 + threadIdx.x;  // < NP*NP/8
  int tile = gid >> 8;                       // (nt*NKC + c)
  int r2 = gid & 255;
  int nt = tile / NKC, c = tile - nt * NKC;
  int ks = r2 >> 6;
  int qm = r2 & 63;
  int q = qm >> 4, m = qm & 15;
  int n = nt * 16 + m;
  int k = c * 128 + ks * 32 + q * 8;
  union { short8 s; unsigned short u[8]; } o;
  if (n < NN && k < NN) {
    const f32x4* a = reinterpret_cast<const f32x4*>(adj + (size_t)n * NN + k);
    f32x4 x0 = __builtin_nontemporal_load(a);
    f32x4 x1 = __builtin_nontemporal_load(a + 1);
    o.u[0] = f2bf(x0.x); o.u[1] = f2bf(x0.y); o.u[2] = f2bf(x0.z); o.u[3] = f2bf(x0.w);
    o.u[4] = f2bf(x1.x); o.u[5] = f2bf(x1.y); o.u[6] = f2bf(x1.z); o.u[7] = f2bf(x1.w);
  } else {
    o.u[0] = 0; o.u[1] = 0; o.u[2] = 0; o.u[3] = 0;
    o.u[4] = 0; o.u[5] = 0; o.u[6] = 0; o.u[7] = 0;
  }
  *reinterpret_cast<short8*>(adjb + (size_t)gid * 8) = o.s;
}

__global__ void k_initx0(const float* __restrict__ in, float* __restrict__ xf,
                         unsigned short* __restrict__ xb) {
  int n = blockIdx.x * 256 + threadIdx.x;
  if (n >= NP) return;
  float v = (n < NN) ? in[(size_t)n * TT] : 0.f;
  xf[n] = v;
  xb[flatXF(0, n)] = f2bf(v);
}

// C^T[f 0..47][node] = sum_k rhs^T[f][k] * A[node][k]
// 512 threads = 8 waves, ALL consumers; wave w owns K slice [w*640, +640).
// BNODE=32: each wave computes TWO 16-node halves per chunk (24 MFMAs,
// 6 accumulators) sharing the SAME 12 X fragments -> X re-read traffic
// per GEMM halves vs BN=16; A/MFMA/output unchanged.
// Issue order: X loads first, A-prefetch(i+1) after, so the MFMAs' wait on
// X leaves the A prefetch in flight across the whole iteration.
// NOTE (R8/R10/R11/R12 lessons): do NOT shrink this K-loop's register
// window. The A double-buffer + 12-wide X batch (~165 VGPR, 1 block/CU)
// beats every 128-VGPR / 2-block variant; runtime-bounded loops or
// megakernel inlining trigger a 128-VGPR serial schedule (3.5-7x slower).
// EPI: 0 = store x1 (f32 row-major + bf16 frag); 1 = gate; 2 = candidate.
template <int EPI, bool USEBF>
__global__ __launch_bounds__(512, 2) void k_gemm(
    const unsigned short* __restrict__ adjb, const float* __restrict__ adjf,
    const unsigned short* __restrict__ rhs,
    float* __restrict__ outF, unsigned short* __restrict__ outB,
    const float* __restrict__ s0F, const float* __restrict__ s1F,
    const float* __restrict__ W, const float* __restrict__ bias,
    float* __restrict__ hT, float* __restrict__ uT,
    float* __restrict__ xoF, unsigned short* __restrict__ xoB,
    const float* __restrict__ inp, const float* __restrict__ Wp,
    const float* __restrict__ bp, float* __restrict__ dout,
    int mode, int tnext, int dstep) {
  constexpr int WC = (EPI == 1) ? 64 : 32;
  // 49152B Pv (8 waves x 48f x 32n) + 6336B x2s; Ws overlays Pv after reduce.
  __shared__ float smemF[PB * 8 + FP * 33];
  float* Pv = smemF;
  float* x2s = smemF + PB * 8;
  float* Ws = smemF;

  const int tid = threadIdx.x;
  const int wave = tid >> 6;
  const int lane = tid & 63;
  const int m = lane & 15;
  const int q = lane >> 4;
  const int nodeBase = blockIdx.x * BNODE;

  f32x4 acc[2][3] = {};
  short8 aCur[2][4], aNxt[2][4];

  auto loadA = [&](int i, short8 (&b)[2][4]) {
    if constexpr (USEBF) {
      const int ch = wave * CPW + i;
#pragma unroll
      for (int h = 0; h < 2; ++h) {
        const unsigned short* a0 =
            adjb + ((size_t)(2 * blockIdx.x + h) * NKC + ch) * ACH + lane * 8;
#pragma unroll
        for (int ks = 0; ks < 4; ++ks)
          b[h][ks] = *reinterpret_cast<const short8*>(a0 + ks * 512);
      }
    } else {
      const int k0 = (wave * CPW + i) * KC;
#pragma unroll
      for (int h = 0; h < 2; ++h) {
        int gnh = nodeBase + h * 16 + m;
        const float* a0 = adjf + (size_t)((gnh < NN) ? gnh : NN - 1) * NN;
#pragma unroll
        for (int ks = 0; ks < 4; ++ks) {
          int kb = k0 + ks * 32 + q * 8;
          union { short8 s; unsigned short u[8]; } p0;
          if (kb + 8 <= NN) {
            float4 x0 = *(const float4*)(a0 + kb);
            float4 x1 = *(const float4*)(a0 + kb + 4);
            p0.u[0] = f2bf(x0.x); p0.u[1] = f2bf(x0.y); p0.u[2] = f2bf(x0.z); p0.u[3] = f2bf(x0.w);
            p0.u[4] = f2bf(x1.x); p0.u[5] = f2bf(x1.y); p0.u[6] = f2bf(x1.z); p0.u[7] = f2bf(x1.w);
          } else {
            for (int j = 0; j < 8; ++j) {
              int k = kb + j;
              p0.u[j] = (k < NN) ? f2bf(a0[k]) : (unsigned short)0;
            }
          }
          b[h][ks] = p0.s;
        }
      }
    }
  };

  loadA(0, aCur);
#pragma unroll
  for (int i = 0; i < CPW; ++i) {
    const int ch = wave * CPW + i;
    short8 cx[12];
    const unsigned short* xb = rhs + (size_t)ch * CHE + lane * 8;
    // X loads first (older in vmcnt order)...
#pragma unroll
    for (int t3 = 0; t3 < 3; ++t3)
#pragma unroll
      for (int ks = 0; ks < 4; ++ks)
        cx[t3 * 4 + ks] = *(const short8*)(xb + t3 * 2048 + ks * 512);
    // ...then the A prefetch: waiting for cx leaves these in flight.
    if (i + 1 < CPW) loadA(i + 1, aNxt);
#pragma unroll
    for (int ks = 0; ks < 4; ++ks) {
#pragma unroll
      for (int h = 0; h < 2; ++h) {
        acc[h][0] = __builtin_amdgcn_mfma_f32_16x16x32_bf16(cx[ks], aCur[h][ks], acc[h][0], 0, 0, 0);
        acc[h][1] = __builtin_amdgcn_mfma_f32_16x16x32_bf16(cx[4 + ks], aCur[h][ks], acc[h][1], 0, 0, 0);
        acc[h][2] = __builtin_amdgcn_mfma_f32_16x16x32_bf16(cx[8 + ks], aCur[h][ks], acc[h][2], 0, 0, 0);
      }
    }
#pragma unroll
    for (int h = 0; h < 2; ++h)
#pragma unroll
      for (int ks = 0; ks < 4; ++ks) aCur[h][ks] = aNxt[h][ks];
  }

#pragma unroll
  for (int h = 0; h < 2; ++h)
#pragma unroll
    for (int t3 = 0; t3 < 3; ++t3)
#pragma unroll
      for (int r = 0; r < 4; ++r)
        Pv[wave * PB + (t3 * 16 + q * 4 + r) * BNODE + h * 16 + m] = acc[h][t3][r];
  __syncthreads();

  if constexpr (EPI == 0) {
    for (int e = tid; e < PB; e += 512) {
      int f = e >> 5, n = e & 31;
      float v = 0.f;
#pragma unroll
      for (int w = 0; w < 8; ++w) v += Pv[w * PB + e];
      int gn2 = nodeBase + n;
      if (gn2 >= NN) v = 0.f;
      outF[(size_t)f * NP + gn2] = v;
      outB[flatXF(f, gn2)] = f2bf(v);
    }
  } else {
    for (int e = tid; e < PB; e += 512) {
      int f = e >> 5, n = e & 31;
      float v = 0.f;
#pragma unroll
      for (int w = 0; w < 8; ++w) v += Pv[w * PB + e];
      x2s[f * 33 + n] = v;
    }
    __syncthreads();
    // Pv is dead; overlay epilogue weights
    for (int i = tid; i < DN * WC; i += 512) Ws[i] = W[i];
    __syncthreads();
    const int nl = tid & 15;
    const int cg = tid >> 4;  // 0..31
    float hwv[2];
#pragma unroll
    for (int nh = 0; nh < 2; ++nh) {
      const int nl2 = nh * 16 + nl;
      const int gn2 = nodeBase + nl2;
      const bool valid = gn2 < NN;
      const int gnc = valid ? gn2 : NN - 1;
      if constexpr (EPI == 1) {
        float a0 = bias[cg], a1 = bias[cg + 32];
        for (int f = 0; f < FR; ++f) {
          float fe = s0F[(size_t)f * NP + gnc];
          a0 += fe * Ws[f * WC + cg]; a1 += fe * Ws[f * WC + cg + 32];
        }
        for (int f = 0; f < FR; ++f) {
          float fe = s1F[(size_t)f * NP + gnc];
          a0 += fe * Ws[(FR + f) * WC + cg]; a1 += fe * Ws[(FR + f) * WC + cg + 32];
        }
        for (int f = 0; f < FR; ++f) {
          float fe = x2s[f * 33 + nl2];
          a0 += fe * Ws[(2 * FR + f) * WC + cg]; a1 += fe * Ws[(2 * FR + f) * WC + cg + 32];
        }
        float r = 1.f / (1.f + expf(-a0));          // r gate (cols 0..31)
        float hv = hT[(size_t)cg * NP + gnc];
        float xc = valid ? r * hv : 0.f;
        xoF[(size_t)(1 + cg) * NP + gn2] = xc;
        xoB[flatXF(1 + cg, gn2)] = f2bf(xc);
        float u = 1.f / (1.f + expf(-a1));          // u gate (cols 32..63)
        uT[(size_t)cg * NP + gn2] = valid ? u : 0.f;
      } else {
        float a0 = bias[cg];
        for (int f = 0; f < FR; ++f) a0 += s0F[(size_t)f * NP + gnc] * Ws[f * WC + cg];
        for (int f = 0; f < FR; ++f) a0 += s1F[(size_t)f * NP + gnc] * Ws[(FR + f) * WC + cg];
        for (int f = 0; f < FR; ++f) a0 += x2s[f * 33 + nl2] * Ws[(2 * FR + f) * WC + cg];
        float c = tanhf(a0);
        float u = uT[(size_t)cg * NP + gnc];
        float h0 = hT[(size_t)cg * NP + gnc];
        float hn = u * h0 + (1.f - u) * c;
        float hw = valid ? hn : 0.f;
        hwv[nh] = hw;
        hT[(size_t)cg * NP + gn2] = hw;
        xoF[(size_t)(1 + cg) * NP + gn2] = hw;
        xoB[flatXF(1 + cg, gn2)] = f2bf(hw);
      }
    }
    if constexpr (EPI == 1) {
      if (tid < BNODE) {
        int g3 = nodeBase + tid;
        float v0 = s0F[g3];
        xoF[g3] = v0;
        xoB[flatXF(0, g3)] = f2bf(v0);
      }
    } else {
      __syncthreads();                 // all x2s reads done
      x2s[cg * 33 + nl] = hwv[0];      // reuse as h scratch [col][node]
      x2s[cg * 33 + 16 + nl] = hwv[1];
      __syncthreads();
      if (tid < BNODE) {
        int g3 = nodeBase + tid;
        bool v3 = g3 < NN;
        float x0 = 0.f;
        if (mode == 0) {
          x0 = v3 ? inp[(size_t)g3 * TT + tnext] : 0.f;
        } else if (mode == 2) {
          float p = bp[0];
          for (int j = 0; j < UU; ++j) p += x2s[j * 33 + tid] * Wp[j];
          if (v3) dout[(size_t)g3 * TT + dstep] = p;
          x0 = v3 ? p : 0.f;
        }
        xoF[g3] = x0;
        xoB[flatXF(0, g3)] = f2bf(x0);
      }
    }
  }
}

extern "C" void kernel_launch(void* const* d_in, const int* in_sizes, int n_in,
                              void* d_out, int out_size, void* d_ws, size_t ws_size,
                              hipStream_t stream) {
  const float* inputs = (const float*)d_in[0];
  const float* adj = (const float*)d_in[2];
  const float* eWg = (const float*)d_in[3];
  const float* eBg = (const float*)d_in[4];
  const float* eWc = (const float*)d_in[5];
  const float* eBc = (const float*)d_in[6];
  const float* dWg = (const float*)d_in[7];
  const float* dBg = (const float*)d_in[8];
  const float* dWc = (const float*)d_in[9];
  const float* dBc = (const float*)d_in[10];
  const float* Wp = (const float*)d_in[11];
  const float* bp = (const float*)d_in[12];
  float* dout = (float*)d_out;

  char* ws = (char*)d_ws;
  size_t o = 0;
  float* xhGf = (float*)(ws + o); o += (size_t)FP * NP * 4;
  unsigned short* xhGb = (unsigned short*)(ws + o); o += (size_t)FP * NP * 2;
  float* xhCf = (float*)(ws + o); o += (size_t)FP * NP * 4;
  unsigned short* xhCb = (unsigned short*)(ws + o); o += (size_t)FP * NP * 2;
  float* x1f = (float*)(ws + o); o += (size_t)FP * NP * 4;
  unsigned short* x1b = (unsigned short*)(ws + o); o += (size_t)FP * NP * 2;
  float* hT = (float*)(ws + o); o += (size_t)UU * NP * 4;
  float* uT = (float*)(ws + o); o += (size_t)UU * NP * 4;
  size_t small = o;
  unsigned short* adjb = (unsigned short*)(ws + o);
  size_t need = o + (size_t)NP * NP * 2;
  bool usebf = ws_size >= need;

  k_zero<<<(int)((small / 16 + 255) / 256), 256, 0, stream>>>((uint4*)ws, (int)(small / 16));
  if (usebf) k_cast2<<<(NP / 8) * NP / 256, 256, 0, stream>>>(adj, adjb);
  k_initx0<<<NP / 256, 256, 0, stream>>>(inputs, xhGf, xhGb);

  auto run = [&](auto ubc) {
    constexpr bool UB = decltype(ubc)::value;
    const unsigned short* ab = UB ? adjb : nullptr;
    for (int t = 0; t < 2 * TT; ++t) {
      bool enc = t < TT;
      const float* Wg = enc ? eWg : dWg;
      const float* Bg = enc ? eBg : dBg;
      const float* Wc = enc ? eWc : dWc;
      const float* Bc = enc ? eBc : dBc;
      int mode, tn = 0, ds = 0;
      if (t < TT - 1) { mode = 0; tn = t + 1; }
      else if (t == TT - 1) { mode = 1; }
      else { mode = 2; ds = t - TT; }

      // K1: x1_g = A @ xh_g
      k_gemm<0, UB><<<GRID_MM, 512, 0, stream>>>(
          ab, adj, xhGb, x1f, x1b,
          nullptr, nullptr, nullptr, nullptr, nullptr, nullptr,
          nullptr, nullptr, nullptr, nullptr, nullptr, nullptr, 0, 0, 0);
      // K2: x2_g = A @ x1_g ; gate epilogue -> xh_c, u
      k_gemm<1, UB><<<GRID_MM, 512, 0, stream>>>(
          ab, adj, x1b, nullptr, nullptr,
          xhGf, x1f, Wg, Bg, hT, uT, xhCf, xhCb,
          nullptr, nullptr, nullptr, nullptr, 0, 0, 0);
      // K3: x1_c = A @ xh_c
      k_gemm<0, UB><<<GRID_MM, 512, 0, stream>>>(
          ab, adj, xhCb, x1f, x1b,
          nullptr, nullptr, nullptr, nullptr, nullptr, nullptr,
          nullptr, nullptr, nullptr, nullptr, nullptr, nullptr, 0, 0, 0);
      // K4: x2_c = A @ x1_c ; candidate epilogue -> h, next xh_g (+ projection)
      k_gemm<2, UB><<<GRID_MM, 512, 0, stream>>>(
          ab, adj, x1b, nullptr, nullptr,
          xhCf, x1f, Wc, Bc, hT, uT, xhGf, xhGb,
          inputs, Wp, bp, dout, mode, tn, ds);
    }
  };
  if (usebf) run(std::integral_constant<bool, true>{});
  else run(std::integral_constant<bool, false>{});
}